// Round 22
// baseline (104.609 us; speedup 1.0000x reference)
//
#include <hip/hip_runtime.h>
#include <math.h>

// ---------------------------------------------------------------------------
// Refine_Attn: 3-level neighborhood-attention pyramid, fp32.
// Stage 1: C=32,  24x48 | Stage 2: C=64, 48x96 | Stage 3: C=128, 96x192
//
// Identities: up2x(y)@Wup+bup feeds only the next qkv matmul ->
//   qkv = up2x(y) @ (Wup@Wqkv) + (bup@Wqkv + bqkv)   (composed on device).
// Launch plan (6 dispatches):
//   compose_qkv1 (union) -> na2d_proj1 -> qkvup2(UP-GEMM) -> na2d_proj2
//   -> qkvup3(UP-GEMM) -> na2d_proj3 (CHW out)
//
// Session ledger (measured):
//   R12/R17 base config:              108.1 / 107.6 us
//   R13 stage-1 mega-fusion:          111.3 us  (regress: 71KB LDS, low occ)
//   R15 +XCD swizzle, BK32 proj:      108.9 us  (neutral; L3-fit, cf. m160)
//   R16 BK32 GEMM:                    112.5 us  (regress: staging regs + LDS)
//   R18 2x8 attn tile (halo 100->72): 107.2 us
//   R20 __expf softmax:               105.7 us
//   R21 compose+qkv1 union:           97.4 us   <- BEST (concurrency win)
// This round: na2d_proj 4x8 tile @512thr (halo 96px/32out = 3.0 loads/px
// vs 4.5; -33% stage-3 K/V traffic, half the blocks).
// ---------------------------------------------------------------------------

// Union kernel: blocks 0..71 compute stage-1 qkv (M=1152,K=32,N=96, CHW
// gather, MT=16); blocks 72..194 compute the weight compositions.
__global__ __launch_bounds__(256) void compose_qkv1(
        const float* __restrict__ x,     // CHW (32,1152)
        const float* __restrict__ Wq1, const float* __restrict__ bq1,
        float* __restrict__ qkv1,        // (1152,96)
        const float* __restrict__ Wu1, const float* __restrict__ bu1,
        const float* __restrict__ Wq2, const float* __restrict__ bq2,
        const float* __restrict__ Wu2, const float* __restrict__ bu2,
        const float* __restrict__ Wq3, const float* __restrict__ bq3,
        float* __restrict__ Wc1, float* __restrict__ bc1,
        float* __restrict__ Wc2, float* __restrict__ bc2) {
    const int tid = threadIdx.x;
    if (blockIdx.x < 72) {
        __shared__ float As[16 * 32];
        const int M = 1152, K = 32, N = 96;
        const int m0 = blockIdx.x * 16;
        for (int idx = tid; idx < 16 * 32; idx += 256) {
            const int r = idx >> 5;
            const int k = idx & 31;
            As[idx] = x[(size_t)k * M + m0 + r];
        }
        __syncthreads();
        const int n = tid;
        if (n < N) {
            float acc[16];
#pragma unroll
            for (int r = 0; r < 16; ++r) acc[r] = bq1[n];
            for (int k = 0; k < K; k += 4) {
                const float* wp = Wq1 + (size_t)k * N + n;
                const float w0 = wp[0];
                const float w1 = wp[N];
                const float w2 = wp[2 * N];
                const float w3 = wp[3 * N];
#pragma unroll
                for (int r = 0; r < 16; ++r) {
                    float4 a4 = *(const float4*)&As[r * K + k];
                    acc[r] = fmaf(a4.x, w0, acc[r]);
                    acc[r] = fmaf(a4.y, w1, acc[r]);
                    acc[r] = fmaf(a4.z, w2, acc[r]);
                    acc[r] = fmaf(a4.w, w3, acc[r]);
                }
            }
            const float qscale = 0.17677669529663687f;  // 1/sqrt(32)
            if (n < 32) {
#pragma unroll
                for (int r = 0; r < 16; ++r) acc[r] *= qscale;
            }
#pragma unroll
            for (int r = 0; r < 16; ++r) qkv1[(size_t)(m0 + r) * N + n] = acc[r];
        }
    } else {
        int idx = (blockIdx.x - 72) * 256 + tid;
        const int R1 = 33 * 192;
        if (idx < R1) {
            const int r = idx / 192;
            const int n = idx - r * 192;
            const float* wp = Wq2 + n;
            const float* a  = (r < 32) ? Wu1 + r * 64 : bu1;
            float s = 0.f;
            for (int k = 0; k < 64; ++k) s = fmaf(a[k], wp[(size_t)k * 192], s);
            if (r < 32) Wc1[r * 192 + n] = s;
            else        bc1[n] = s + bq2[n];
        } else {
            idx -= R1;
            if (idx >= 65 * 384) return;
            const int r = idx / 384;
            const int n = idx - r * 384;
            const float* wp = Wq3 + n;
            const float* a  = (r < 64) ? Wu2 + r * 128 : bu2;
            float s = 0.f;
            for (int k = 0; k < 128; ++k) s = fmaf(a[k], wp[(size_t)k * 384], s);
            if (r < 64) Wc2[r * 384 + n] = s;
            else        bc2[n] = s + bq3[n];
        }
    }
}

// Register-tiled GEMM: out = A(M,K) @ Wt(K,N) + bias; first qcols cols scaled
// by qscale after bias. Block tile BM x BN, BK=16, 256 thr, thread tile
// RT x NT (RT=BM/16, BN=16*NT). UP: A rows are bilinear 2x-upsampled y (Hs,Ws,K).
template <int BM, int BN, int NT, int TRANS, int UP>
__global__ __launch_bounds__(256) void gemm_rt(
        const float* __restrict__ A, const float* __restrict__ Wt,
        const float* __restrict__ bias, float* __restrict__ out,
        int M, int K, int N, int qcols, float qscale, int Hs, int Ws) {
    constexpr int BK = 16;
    constexpr int RT = BM / 16;
    constexpr int AIT = (BM * BK) / (4 * 256);
    constexpr int BIT = (BK * BN) / (4 * 256);
    __shared__ float As[BK][BM + 4];
    __shared__ float Bs[BK][BN + 4];
    const int tid = threadIdx.x;
    const int tn = tid >> 4;
    const int tm = tid & 15;
    const int m0 = blockIdx.x * BM;
    const int n0 = blockIdx.y * BN;

    const int sa_m = tid >> 2;
    const int sa_k = (tid & 3) << 2;

    const float* ybase[AIT][4];
    float uwh[AIT], uww[AIT];
    if (UP) {
        const int Wd = 2 * Ws, Hd = 2 * Hs;
#pragma unroll
        for (int i = 0; i < AIT; ++i) {
            const int row = m0 + sa_m + i * 64;
            const int h2 = row / Wd;
            const int w2 = row - h2 * Wd;
            const float ph = (float)h2 * (float)(Hs - 1) / (float)(Hd - 1);
            const int h0i = (int)ph;
            const int h1i = min(h0i + 1, Hs - 1);
            uwh[i] = ph - (float)h0i;
            const float pw = (float)w2 * (float)(Ws - 1) / (float)(Wd - 1);
            const int w0i = (int)pw;
            const int w1i = min(w0i + 1, Ws - 1);
            uww[i] = pw - (float)w0i;
            ybase[i][0] = A + ((size_t)h0i * Ws + w0i) * K;
            ybase[i][1] = A + ((size_t)h0i * Ws + w1i) * K;
            ybase[i][2] = A + ((size_t)h1i * Ws + w0i) * K;
            ybase[i][3] = A + ((size_t)h1i * Ws + w1i) * K;
        }
    }

    float acc[RT][NT];
#pragma unroll
    for (int r = 0; r < RT; ++r)
#pragma unroll
        for (int c = 0; c < NT; ++c) acc[r][c] = 0.f;

    for (int k0 = 0; k0 < K; k0 += BK) {
        float4 av[AIT];
#pragma unroll
        for (int i = 0; i < AIT; ++i) {
            if (UP) {
                const float4 v00 = *(const float4*)(ybase[i][0] + k0 + sa_k);
                const float4 v01 = *(const float4*)(ybase[i][1] + k0 + sa_k);
                const float4 v10 = *(const float4*)(ybase[i][2] + k0 + sa_k);
                const float4 v11 = *(const float4*)(ybase[i][3] + k0 + sa_k);
                const float wh = uwh[i], ww = uww[i];
                av[i].x = (v00.x * (1.f - wh) + v10.x * wh) * (1.f - ww) +
                          (v01.x * (1.f - wh) + v11.x * wh) * ww;
                av[i].y = (v00.y * (1.f - wh) + v10.y * wh) * (1.f - ww) +
                          (v01.y * (1.f - wh) + v11.y * wh) * ww;
                av[i].z = (v00.z * (1.f - wh) + v10.z * wh) * (1.f - ww) +
                          (v01.z * (1.f - wh) + v11.z * wh) * ww;
                av[i].w = (v00.w * (1.f - wh) + v10.w * wh) * (1.f - ww) +
                          (v01.w * (1.f - wh) + v11.w * wh) * ww;
            } else {
                av[i] = *(const float4*)(A + (size_t)(m0 + sa_m + i * 64) * K + k0 + sa_k);
            }
        }
        float4 bv[BIT];
#pragma unroll
        for (int i = 0; i < BIT; ++i) {
            const int f  = tid + i * 256;
            const int kl = f / (BN / 4);
            const int n4 = f - kl * (BN / 4);
            bv[i] = *(const float4*)(Wt + (size_t)(k0 + kl) * N + n0 + n4 * 4);
        }
        __syncthreads();
#pragma unroll
        for (int i = 0; i < AIT; ++i) {
            As[sa_k + 0][sa_m + i * 64] = av[i].x;
            As[sa_k + 1][sa_m + i * 64] = av[i].y;
            As[sa_k + 2][sa_m + i * 64] = av[i].z;
            As[sa_k + 3][sa_m + i * 64] = av[i].w;
        }
#pragma unroll
        for (int i = 0; i < BIT; ++i) {
            const int f  = tid + i * 256;
            const int kl = f / (BN / 4);
            const int n4 = f - kl * (BN / 4);
            *(float4*)&Bs[kl][n4 * 4] = bv[i];
        }
        __syncthreads();
#pragma unroll
        for (int kk = 0; kk < BK; ++kk) {
            float a[RT];
#pragma unroll
            for (int q = 0; q < RT / 4; ++q) {
                float4 t = *(const float4*)&As[kk][tm * RT + q * 4];
                a[q * 4 + 0] = t.x; a[q * 4 + 1] = t.y;
                a[q * 4 + 2] = t.z; a[q * 4 + 3] = t.w;
            }
            float b[NT];
#pragma unroll
            for (int q = 0; q < NT / 4; ++q) {
                float4 t = *(const float4*)&Bs[kk][tn * NT + q * 4];
                b[q * 4 + 0] = t.x; b[q * 4 + 1] = t.y;
                b[q * 4 + 2] = t.z; b[q * 4 + 3] = t.w;
            }
#pragma unroll
            for (int r = 0; r < RT; ++r)
#pragma unroll
                for (int c = 0; c < NT; ++c)
                    acc[r][c] = fmaf(a[r], b[c], acc[r][c]);
        }
    }

#pragma unroll
    for (int c = 0; c < NT; ++c) {
        const int n = n0 + tn * NT + c;
        const float bz = bias[n];
        const float sc = (n < qcols) ? qscale : 1.f;
#pragma unroll
        for (int r = 0; r < RT; ++r) acc[r][c] = (acc[r][c] + bz) * sc;
    }
    if (TRANS) {
#pragma unroll
        for (int c = 0; c < NT; ++c) {
            const int n = n0 + tn * NT + c;
            float* op = out + (size_t)n * M + m0 + tm * RT;
#pragma unroll
            for (int q = 0; q < RT / 4; ++q)
                *(float4*)(op + q * 4) = make_float4(acc[q * 4][c], acc[q * 4 + 1][c],
                                                     acc[q * 4 + 2][c], acc[q * 4 + 3][c]);
        }
    } else {
#pragma unroll
        for (int r = 0; r < RT; ++r) {
            float* op = out + (size_t)(m0 + tm * RT + r) * N + n0 + tn * NT;
#pragma unroll
            for (int q = 0; q < NT / 4; ++q)
                *(float4*)(op + q * 4) = make_float4(acc[r][q * 4], acc[r][q * 4 + 1],
                                                     acc[r][q * 4 + 2], acc[r][q * 4 + 3]);
        }
    }
}

template <int VPL>
__device__ inline void loadv(const float* __restrict__ p, float* d) {
    if constexpr (VPL == 2) {
        float2 t = *(const float2*)p;
        d[0] = t.x; d[1] = t.y;
    } else if constexpr (VPL == 4) {
        float4 t = *(const float4*)p;
        d[0] = t.x; d[1] = t.y; d[2] = t.z; d[3] = t.w;
    } else {
        float4 t0 = *(const float4*)p;
        float4 t1 = *(const float4*)(p + 4);
        d[0] = t0.x; d[1] = t0.y; d[2] = t0.z; d[3] = t0.w;
        d[4] = t1.x; d[5] = t1.y; d[6] = t1.z; d[7] = t1.w;
    }
}

// Fused neighborhood attention + proj. 512 thr = 8 waves x 4 px = 32 px.
// Block = 4x8 pixel tile (halo 8x12=96 px for 32 outputs = 3.0 px-loads/px).
// Grid = (H/4)*(W/8) = M/32. Softmax uses __expf.
template <int C, int TRANS>
__global__ __launch_bounds__(512) void na2d_proj(
        const float* __restrict__ qkv, const float* __restrict__ rpb,
        const float* __restrict__ Wp, const float* __restrict__ bp,
        float* __restrict__ out, int H, int W, int M) {
    constexpr int VPL = C / 16;
    constexpr int NT  = C / 16;
    __shared__ float att_s[32][C + 4];
    __shared__ float Bs[16][C];
    const int tid  = threadIdx.x;
    const int lane = tid & 63;
    const int g    = lane >> 4;
    const int li   = lane & 15;
    const int wave = tid >> 6;
    const int lp   = wave * 4 + g;           // local pixel 0..31
    const int tpr  = W >> 3;                 // tiles per row-band
    const int trow = blockIdx.x / tpr;
    const int tcol = blockIdx.x - trow * tpr;
    const int h    = trow * 4 + (lp >> 3);
    const int w    = tcol * 8 + (lp & 7);
    const int pix  = h * W + w;
    const int h0 = min(max(h - 2, 0), H - 5);
    const int w0 = min(max(w - 2, 0), W - 5);
    const int cb = li * VPL;
    const int bih = h0 - h + 4;
    const int biw = w0 - w + 4;

    float qf[VPL];
    loadv<VPL>(qkv + (size_t)pix * (3 * C) + cb, qf);

    float p[25];
#pragma unroll
    for (int jr = 0; jr < 5; ++jr) {
        const float* rowk = qkv + (size_t)((h0 + jr) * W + w0) * (3 * C) + C + cb;
        float kf[5][VPL];
#pragma unroll
        for (int jc = 0; jc < 5; ++jc) loadv<VPL>(rowk + jc * 3 * C, kf[jc]);
#pragma unroll
        for (int jc = 0; jc < 5; ++jc) {
            float s = qf[0] * kf[jc][0];
#pragma unroll
            for (int v = 1; v < VPL; ++v) s = fmaf(qf[v], kf[jc][v], s);
            p[jr * 5 + jc] = s;
        }
    }
#pragma unroll
    for (int jr = 0; jr < 5; ++jr)
#pragma unroll
        for (int jc = 0; jc < 5; ++jc) {
            const int j = jr * 5 + jc;
            float v = p[j];
            v += __shfl_xor(v, 1);
            v += __shfl_xor(v, 2);
            v += __shfl_xor(v, 4);
            v += __shfl_xor(v, 8);
            p[j] = v + rpb[(bih + jr) * 9 + (biw + jc)];
        }
    float mx = p[0];
#pragma unroll
    for (int j = 1; j < 25; ++j) mx = fmaxf(mx, p[j]);
    float sum = 0.f;
#pragma unroll
    for (int j = 0; j < 25; ++j) {
        p[j] = __expf(p[j] - mx);
        sum += p[j];
    }
    const float inv = 1.f / sum;

    float a[VPL];
#pragma unroll
    for (int v = 0; v < VPL; ++v) a[v] = 0.f;
#pragma unroll
    for (int jr = 0; jr < 5; ++jr) {
        const float* rowv = qkv + (size_t)((h0 + jr) * W + w0) * (3 * C) + 2 * C + cb;
        float vf[5][VPL];
#pragma unroll
        for (int jc = 0; jc < 5; ++jc) loadv<VPL>(rowv + jc * 3 * C, vf[jc]);
#pragma unroll
        for (int jc = 0; jc < 5; ++jc)
#pragma unroll
            for (int v = 0; v < VPL; ++v) a[v] = fmaf(p[jr * 5 + jc], vf[jc][v], a[v]);
    }
#pragma unroll
    for (int v = 0; v < VPL; ++v) att_s[lp][cb + v] = a[v] * inv;

    // ---- proj: 32xC @ CxC + bias (512 threads: 32 rows x 16 col-groups) ----
    const int tm = tid & 31;                 // row 0..31
    const int tn = tid >> 5;                 // col group 0..15
    const int pixm = (trow * 4 + (tm >> 3)) * W + tcol * 8 + (tm & 7);
    constexpr int WPT = C / 32;              // Bs floats staged per thread
    const int skl = tid >> 5;                // k-row 0..15
    const int snn = (tid & 31) * WPT;        // col base
    float acc[NT];
#pragma unroll
    for (int c = 0; c < NT; ++c) acc[c] = bp[tn * NT + c];

    for (int k0 = 0; k0 < C; k0 += 16) {
        float tmp[WPT];
        {
            const float* src = Wp + (size_t)(k0 + skl) * C + snn;
#pragma unroll
            for (int t = 0; t < WPT; ++t) tmp[t] = src[t];
        }
        __syncthreads();   // prev tile's Bs reads done; iter0: att_s visible
#pragma unroll
        for (int t = 0; t < WPT; ++t) Bs[skl][snn + t] = tmp[t];
        __syncthreads();
#pragma unroll
        for (int kk = 0; kk < 16; ++kk) {
            const float av = att_s[tm][k0 + kk];
            const float* bsp = &Bs[kk][tn * NT];
#pragma unroll
            for (int c = 0; c < NT; ++c) acc[c] = fmaf(av, bsp[c], acc[c]);
        }
    }

    if (TRANS) {
#pragma unroll
        for (int c = 0; c < NT; ++c)
            out[(size_t)(tn * NT + c) * M + pixm] = acc[c];
    } else {
        float* op = out + (size_t)pixm * C + tn * NT;
#pragma unroll
        for (int c = 0; c < NT; ++c) op[c] = acc[c];
    }
}

extern "C" void kernel_launch(void* const* d_in, const int* in_sizes, int n_in,
                              void* d_out, int out_size, void* d_ws, size_t ws_size,
                              hipStream_t stream) {
    const float* attn    = (const float*)d_in[0];
    const float* w_qkv1  = (const float*)d_in[1];
    const float* b_qkv1  = (const float*)d_in[2];
    const float* w_proj1 = (const float*)d_in[3];
    const float* b_proj1 = (const float*)d_in[4];
    const float* rpb1    = (const float*)d_in[5];
    const float* w_qkv2  = (const float*)d_in[6];
    const float* b_qkv2  = (const float*)d_in[7];
    const float* w_proj2 = (const float*)d_in[8];
    const float* b_proj2 = (const float*)d_in[9];
    const float* rpb2    = (const float*)d_in[10];
    const float* w_qkv3  = (const float*)d_in[11];
    const float* b_qkv3  = (const float*)d_in[12];
    const float* w_proj3 = (const float*)d_in[13];
    const float* b_proj3 = (const float*)d_in[14];
    const float* rpb3    = (const float*)d_in[15];
    const float* w_up1   = (const float*)d_in[16];
    const float* b_up1   = (const float*)d_in[17];
    const float* w_up2   = (const float*)d_in[18];
    const float* b_up2   = (const float*)d_in[19];
    float* out = (float*)d_out;

    float* ws   = (float*)d_ws;
    float* bufB = ws + 2359296;              // qkv   (max 18432*384)
    float* bufD = bufB + 7077888;            // y     (max 4608*64)
    float* wc1  = bufD + 294912;             // 32x192 composed up1->qkv2
    float* bc1  = wc1 + 6144;                // 192
    float* wc2  = bc1 + 192;                 // 64x384 composed up2->qkv3
    float* bc2  = wc2 + 24576;               // 384

    // ---- union: weight composition + stage-1 qkv (independent work) ----
    compose_qkv1<<<72 + 123, 256, 0, stream>>>(
        attn, w_qkv1, b_qkv1, bufB,
        w_up1, b_up1, w_qkv2, b_qkv2, w_up2, b_up2, w_qkv3, b_qkv3,
        wc1, bc1, wc2, bc2);

    // ---- Stage 1 attention+proj: C=32, 24x48, M=1152 ----
    {
        const int H = 24, W = 48, M = H * W;
        na2d_proj<32, 0><<<M / 32, 512, 0, stream>>>(
            bufB, rpb1, w_proj1, b_proj1, bufD, H, W, M);
    }
    // ---- Stage 2: C=64, 48x96, M=4608; qkv2 = up2x(y1) @ wc1 + bc1 ----
    {
        const int H = 48, W = 96, C = 64, M = H * W;
        gemm_rt<64, 64, 4, 0, 1><<<dim3(M / 64, 3), 256, 0, stream>>>(
            bufD, wc1, bc1, bufB, M, 32, 3 * C, C, 1.f / sqrtf((float)C), 24, 48);
        na2d_proj<64, 0><<<M / 32, 512, 0, stream>>>(
            bufB, rpb2, w_proj2, b_proj2, bufD, H, W, M);
    }
    // ---- Stage 3: C=128, 96x192, M=18432; qkv3 = up2x(y2) @ wc2 + bc2 ----
    {
        const int H = 96, W = 192, C = 128, M = H * W;
        gemm_rt<128, 128, 8, 0, 1><<<dim3(M / 128, 3), 256, 0, stream>>>(
            bufD, wc2, bc2, bufB, M, 64, 3 * C, C, 1.f / sqrtf((float)C), 48, 96);
        na2d_proj<128, 1><<<M / 32, 512, 0, stream>>>(
            bufB, rpb3, w_proj3, b_proj3, out, H, W, M);  // -> CHW
    }
}

// Round 24
// 97.215 us; speedup vs baseline: 1.0761x; 1.0761x over previous
//
#include <hip/hip_runtime.h>
#include <math.h>

// ---------------------------------------------------------------------------
// Refine_Attn: 3-level neighborhood-attention pyramid, fp32.
// Stage 1: C=32,  24x48 | Stage 2: C=64, 48x96 | Stage 3: C=128, 96x192
//
// Identities: up2x(y)@Wup+bup feeds only the next qkv matmul ->
//   qkv = up2x(y) @ (Wup@Wqkv) + (bup@Wqkv + bqkv)   (composed on device).
// Launch plan (6 dispatches):
//   compose_qkv1 (union) -> na2d_proj1 -> qkvup2(UP-GEMM) -> na2d_proj2
//   -> qkvup3(UP-GEMM) -> na2d_proj3 (CHW out)
//
// Session ledger (measured):
//   R12/R17 base config:              108.1 / 107.6 us
//   R13 stage-1 mega-fusion:          111.3 us  (regress: 71KB LDS, low occ)
//   R15 +XCD swizzle, BK32 proj:      108.9 us  (neutral; L3-fit, cf. m160)
//   R16 BK32 GEMM:                    112.5 us  (regress: staging regs + LDS)
//   R18 2x8 attn tile (halo 100->72): 107.2 us
//   R20 __expf softmax:               105.7 us
//   R21 compose+qkv1 union:           97.4 us   <- BEST
//   R22 4x8 tile @512thr:             104.6 us  (regress: 8-wave barriers,
//                                                half the blocks -> less TLP)
// -> reverted na2d_proj to R21-exact 2x8 @256thr.
// ---------------------------------------------------------------------------

// Union kernel: blocks 0..71 compute stage-1 qkv (M=1152,K=32,N=96, CHW
// gather, MT=16); blocks 72..194 compute the weight compositions.
__global__ __launch_bounds__(256) void compose_qkv1(
        const float* __restrict__ x,     // CHW (32,1152)
        const float* __restrict__ Wq1, const float* __restrict__ bq1,
        float* __restrict__ qkv1,        // (1152,96)
        const float* __restrict__ Wu1, const float* __restrict__ bu1,
        const float* __restrict__ Wq2, const float* __restrict__ bq2,
        const float* __restrict__ Wu2, const float* __restrict__ bu2,
        const float* __restrict__ Wq3, const float* __restrict__ bq3,
        float* __restrict__ Wc1, float* __restrict__ bc1,
        float* __restrict__ Wc2, float* __restrict__ bc2) {
    const int tid = threadIdx.x;
    if (blockIdx.x < 72) {
        __shared__ float As[16 * 32];
        const int M = 1152, K = 32, N = 96;
        const int m0 = blockIdx.x * 16;
        for (int idx = tid; idx < 16 * 32; idx += 256) {
            const int r = idx >> 5;
            const int k = idx & 31;
            As[idx] = x[(size_t)k * M + m0 + r];
        }
        __syncthreads();
        const int n = tid;
        if (n < N) {
            float acc[16];
#pragma unroll
            for (int r = 0; r < 16; ++r) acc[r] = bq1[n];
            for (int k = 0; k < K; k += 4) {
                const float* wp = Wq1 + (size_t)k * N + n;
                const float w0 = wp[0];
                const float w1 = wp[N];
                const float w2 = wp[2 * N];
                const float w3 = wp[3 * N];
#pragma unroll
                for (int r = 0; r < 16; ++r) {
                    float4 a4 = *(const float4*)&As[r * K + k];
                    acc[r] = fmaf(a4.x, w0, acc[r]);
                    acc[r] = fmaf(a4.y, w1, acc[r]);
                    acc[r] = fmaf(a4.z, w2, acc[r]);
                    acc[r] = fmaf(a4.w, w3, acc[r]);
                }
            }
            const float qscale = 0.17677669529663687f;  // 1/sqrt(32)
            if (n < 32) {
#pragma unroll
                for (int r = 0; r < 16; ++r) acc[r] *= qscale;
            }
#pragma unroll
            for (int r = 0; r < 16; ++r) qkv1[(size_t)(m0 + r) * N + n] = acc[r];
        }
    } else {
        int idx = (blockIdx.x - 72) * 256 + tid;
        const int R1 = 33 * 192;
        if (idx < R1) {
            const int r = idx / 192;
            const int n = idx - r * 192;
            const float* wp = Wq2 + n;
            const float* a  = (r < 32) ? Wu1 + r * 64 : bu1;
            float s = 0.f;
            for (int k = 0; k < 64; ++k) s = fmaf(a[k], wp[(size_t)k * 192], s);
            if (r < 32) Wc1[r * 192 + n] = s;
            else        bc1[n] = s + bq2[n];
        } else {
            idx -= R1;
            if (idx >= 65 * 384) return;
            const int r = idx / 384;
            const int n = idx - r * 384;
            const float* wp = Wq3 + n;
            const float* a  = (r < 64) ? Wu2 + r * 128 : bu2;
            float s = 0.f;
            for (int k = 0; k < 128; ++k) s = fmaf(a[k], wp[(size_t)k * 384], s);
            if (r < 64) Wc2[r * 384 + n] = s;
            else        bc2[n] = s + bq3[n];
        }
    }
}

// Register-tiled GEMM: out = A(M,K) @ Wt(K,N) + bias; first qcols cols scaled
// by qscale after bias. Block tile BM x BN, BK=16, 256 thr, thread tile
// RT x NT (RT=BM/16, BN=16*NT). UP: A rows are bilinear 2x-upsampled y (Hs,Ws,K).
template <int BM, int BN, int NT, int TRANS, int UP>
__global__ __launch_bounds__(256) void gemm_rt(
        const float* __restrict__ A, const float* __restrict__ Wt,
        const float* __restrict__ bias, float* __restrict__ out,
        int M, int K, int N, int qcols, float qscale, int Hs, int Ws) {
    constexpr int BK = 16;
    constexpr int RT = BM / 16;
    constexpr int AIT = (BM * BK) / (4 * 256);
    constexpr int BIT = (BK * BN) / (4 * 256);
    __shared__ float As[BK][BM + 4];
    __shared__ float Bs[BK][BN + 4];
    const int tid = threadIdx.x;
    const int tn = tid >> 4;
    const int tm = tid & 15;
    const int m0 = blockIdx.x * BM;
    const int n0 = blockIdx.y * BN;

    const int sa_m = tid >> 2;
    const int sa_k = (tid & 3) << 2;

    const float* ybase[AIT][4];
    float uwh[AIT], uww[AIT];
    if (UP) {
        const int Wd = 2 * Ws, Hd = 2 * Hs;
#pragma unroll
        for (int i = 0; i < AIT; ++i) {
            const int row = m0 + sa_m + i * 64;
            const int h2 = row / Wd;
            const int w2 = row - h2 * Wd;
            const float ph = (float)h2 * (float)(Hs - 1) / (float)(Hd - 1);
            const int h0i = (int)ph;
            const int h1i = min(h0i + 1, Hs - 1);
            uwh[i] = ph - (float)h0i;
            const float pw = (float)w2 * (float)(Ws - 1) / (float)(Wd - 1);
            const int w0i = (int)pw;
            const int w1i = min(w0i + 1, Ws - 1);
            uww[i] = pw - (float)w0i;
            ybase[i][0] = A + ((size_t)h0i * Ws + w0i) * K;
            ybase[i][1] = A + ((size_t)h0i * Ws + w1i) * K;
            ybase[i][2] = A + ((size_t)h1i * Ws + w0i) * K;
            ybase[i][3] = A + ((size_t)h1i * Ws + w1i) * K;
        }
    }

    float acc[RT][NT];
#pragma unroll
    for (int r = 0; r < RT; ++r)
#pragma unroll
        for (int c = 0; c < NT; ++c) acc[r][c] = 0.f;

    for (int k0 = 0; k0 < K; k0 += BK) {
        float4 av[AIT];
#pragma unroll
        for (int i = 0; i < AIT; ++i) {
            if (UP) {
                const float4 v00 = *(const float4*)(ybase[i][0] + k0 + sa_k);
                const float4 v01 = *(const float4*)(ybase[i][1] + k0 + sa_k);
                const float4 v10 = *(const float4*)(ybase[i][2] + k0 + sa_k);
                const float4 v11 = *(const float4*)(ybase[i][3] + k0 + sa_k);
                const float wh = uwh[i], ww = uww[i];
                av[i].x = (v00.x * (1.f - wh) + v10.x * wh) * (1.f - ww) +
                          (v01.x * (1.f - wh) + v11.x * wh) * ww;
                av[i].y = (v00.y * (1.f - wh) + v10.y * wh) * (1.f - ww) +
                          (v01.y * (1.f - wh) + v11.y * wh) * ww;
                av[i].z = (v00.z * (1.f - wh) + v10.z * wh) * (1.f - ww) +
                          (v01.z * (1.f - wh) + v11.z * wh) * ww;
                av[i].w = (v00.w * (1.f - wh) + v10.w * wh) * (1.f - ww) +
                          (v01.w * (1.f - wh) + v11.w * wh) * ww;
            } else {
                av[i] = *(const float4*)(A + (size_t)(m0 + sa_m + i * 64) * K + k0 + sa_k);
            }
        }
        float4 bv[BIT];
#pragma unroll
        for (int i = 0; i < BIT; ++i) {
            const int f  = tid + i * 256;
            const int kl = f / (BN / 4);
            const int n4 = f - kl * (BN / 4);
            bv[i] = *(const float4*)(Wt + (size_t)(k0 + kl) * N + n0 + n4 * 4);
        }
        __syncthreads();
#pragma unroll
        for (int i = 0; i < AIT; ++i) {
            As[sa_k + 0][sa_m + i * 64] = av[i].x;
            As[sa_k + 1][sa_m + i * 64] = av[i].y;
            As[sa_k + 2][sa_m + i * 64] = av[i].z;
            As[sa_k + 3][sa_m + i * 64] = av[i].w;
        }
#pragma unroll
        for (int i = 0; i < BIT; ++i) {
            const int f  = tid + i * 256;
            const int kl = f / (BN / 4);
            const int n4 = f - kl * (BN / 4);
            *(float4*)&Bs[kl][n4 * 4] = bv[i];
        }
        __syncthreads();
#pragma unroll
        for (int kk = 0; kk < BK; ++kk) {
            float a[RT];
#pragma unroll
            for (int q = 0; q < RT / 4; ++q) {
                float4 t = *(const float4*)&As[kk][tm * RT + q * 4];
                a[q * 4 + 0] = t.x; a[q * 4 + 1] = t.y;
                a[q * 4 + 2] = t.z; a[q * 4 + 3] = t.w;
            }
            float b[NT];
#pragma unroll
            for (int q = 0; q < NT / 4; ++q) {
                float4 t = *(const float4*)&Bs[kk][tn * NT + q * 4];
                b[q * 4 + 0] = t.x; b[q * 4 + 1] = t.y;
                b[q * 4 + 2] = t.z; b[q * 4 + 3] = t.w;
            }
#pragma unroll
            for (int r = 0; r < RT; ++r)
#pragma unroll
                for (int c = 0; c < NT; ++c)
                    acc[r][c] = fmaf(a[r], b[c], acc[r][c]);
        }
    }

#pragma unroll
    for (int c = 0; c < NT; ++c) {
        const int n = n0 + tn * NT + c;
        const float bz = bias[n];
        const float sc = (n < qcols) ? qscale : 1.f;
#pragma unroll
        for (int r = 0; r < RT; ++r) acc[r][c] = (acc[r][c] + bz) * sc;
    }
    if (TRANS) {
#pragma unroll
        for (int c = 0; c < NT; ++c) {
            const int n = n0 + tn * NT + c;
            float* op = out + (size_t)n * M + m0 + tm * RT;
#pragma unroll
            for (int q = 0; q < RT / 4; ++q)
                *(float4*)(op + q * 4) = make_float4(acc[q * 4][c], acc[q * 4 + 1][c],
                                                     acc[q * 4 + 2][c], acc[q * 4 + 3][c]);
        }
    } else {
#pragma unroll
        for (int r = 0; r < RT; ++r) {
            float* op = out + (size_t)(m0 + tm * RT + r) * N + n0 + tn * NT;
#pragma unroll
            for (int q = 0; q < NT / 4; ++q)
                *(float4*)(op + q * 4) = make_float4(acc[r][q * 4], acc[r][q * 4 + 1],
                                                     acc[r][q * 4 + 2], acc[r][q * 4 + 3]);
        }
    }
}

template <int VPL>
__device__ inline void loadv(const float* __restrict__ p, float* d) {
    if constexpr (VPL == 2) {
        float2 t = *(const float2*)p;
        d[0] = t.x; d[1] = t.y;
    } else if constexpr (VPL == 4) {
        float4 t = *(const float4*)p;
        d[0] = t.x; d[1] = t.y; d[2] = t.z; d[3] = t.w;
    } else {
        float4 t0 = *(const float4*)p;
        float4 t1 = *(const float4*)(p + 4);
        d[0] = t0.x; d[1] = t0.y; d[2] = t0.z; d[3] = t0.w;
        d[4] = t1.x; d[5] = t1.y; d[6] = t1.z; d[7] = t1.w;
    }
}

// Fused neighborhood attention + proj. 256 thr = 4 waves x 4 px.
// Block = 2x8 pixel tile (halo 6x12=72 px). Grid = (H/2)*(W/8) = M/16.
// Softmax uses __expf (fast exp): output-scale error ~3e-13 << 5.9e-9 thr.
template <int C, int TRANS>
__global__ __launch_bounds__(256) void na2d_proj(
        const float* __restrict__ qkv, const float* __restrict__ rpb,
        const float* __restrict__ Wp, const float* __restrict__ bp,
        float* __restrict__ out, int H, int W, int M) {
    constexpr int VPL = C / 16;
    constexpr int NT  = C / 16;
    __shared__ float att_s[16][C + 4];
    __shared__ float Bs[16][C];
    const int tid  = threadIdx.x;
    const int lane = tid & 63;
    const int g    = lane >> 4;
    const int li   = lane & 15;
    const int wave = tid >> 6;
    const int lp   = wave * 4 + g;           // local pixel 0..15
    const int tpr  = W >> 3;                 // tiles per row-band
    const int trow = blockIdx.x / tpr;
    const int tcol = blockIdx.x - trow * tpr;
    const int h    = trow * 2 + (lp >> 3);
    const int w    = tcol * 8 + (lp & 7);
    const int pix  = h * W + w;
    const int h0 = min(max(h - 2, 0), H - 5);
    const int w0 = min(max(w - 2, 0), W - 5);
    const int cb = li * VPL;
    const int bih = h0 - h + 4;
    const int biw = w0 - w + 4;

    float qf[VPL];
    loadv<VPL>(qkv + (size_t)pix * (3 * C) + cb, qf);

    float p[25];
#pragma unroll
    for (int jr = 0; jr < 5; ++jr) {
        const float* rowk = qkv + (size_t)((h0 + jr) * W + w0) * (3 * C) + C + cb;
        float kf[5][VPL];
#pragma unroll
        for (int jc = 0; jc < 5; ++jc) loadv<VPL>(rowk + jc * 3 * C, kf[jc]);
#pragma unroll
        for (int jc = 0; jc < 5; ++jc) {
            float s = qf[0] * kf[jc][0];
#pragma unroll
            for (int v = 1; v < VPL; ++v) s = fmaf(qf[v], kf[jc][v], s);
            p[jr * 5 + jc] = s;
        }
    }
#pragma unroll
    for (int jr = 0; jr < 5; ++jr)
#pragma unroll
        for (int jc = 0; jc < 5; ++jc) {
            const int j = jr * 5 + jc;
            float v = p[j];
            v += __shfl_xor(v, 1);
            v += __shfl_xor(v, 2);
            v += __shfl_xor(v, 4);
            v += __shfl_xor(v, 8);
            p[j] = v + rpb[(bih + jr) * 9 + (biw + jc)];
        }
    float mx = p[0];
#pragma unroll
    for (int j = 1; j < 25; ++j) mx = fmaxf(mx, p[j]);
    float sum = 0.f;
#pragma unroll
    for (int j = 0; j < 25; ++j) {
        p[j] = __expf(p[j] - mx);
        sum += p[j];
    }
    const float inv = 1.f / sum;

    float a[VPL];
#pragma unroll
    for (int v = 0; v < VPL; ++v) a[v] = 0.f;
#pragma unroll
    for (int jr = 0; jr < 5; ++jr) {
        const float* rowv = qkv + (size_t)((h0 + jr) * W + w0) * (3 * C) + 2 * C + cb;
        float vf[5][VPL];
#pragma unroll
        for (int jc = 0; jc < 5; ++jc) loadv<VPL>(rowv + jc * 3 * C, vf[jc]);
#pragma unroll
        for (int jc = 0; jc < 5; ++jc)
#pragma unroll
            for (int v = 0; v < VPL; ++v) a[v] = fmaf(p[jr * 5 + jc], vf[jc][v], a[v]);
    }
#pragma unroll
    for (int v = 0; v < VPL; ++v) att_s[lp][cb + v] = a[v] * inv;

    // ---- proj: 16xC @ CxC + bias ----
    const int tm = tid & 15;
    const int tn = tid >> 4;
    // global pixel for att_s row tm (same 2x8 mapping)
    const int pixm = (trow * 2 + (tm >> 3)) * W + tcol * 8 + (tm & 7);
    constexpr int WPT = C / 16;
    const int skl = tid >> 4;
    const int snn = (tid & 15) * WPT;
    float acc[NT];
#pragma unroll
    for (int c = 0; c < NT; ++c) acc[c] = bp[tn * NT + c];

    for (int k0 = 0; k0 < C; k0 += 16) {
        float tmp[WPT];
        {
            const float* src = Wp + (size_t)(k0 + skl) * C + snn;
#pragma unroll
            for (int t = 0; t < WPT; ++t) tmp[t] = src[t];
        }
        __syncthreads();
#pragma unroll
        for (int t = 0; t < WPT; ++t) Bs[skl][snn + t] = tmp[t];
        __syncthreads();
#pragma unroll
        for (int kk = 0; kk < 16; ++kk) {
            const float av = att_s[tm][k0 + kk];
            const float* bsp = &Bs[kk][tn * NT];
#pragma unroll
            for (int c = 0; c < NT; ++c) acc[c] = fmaf(av, bsp[c], acc[c]);
        }
    }

    if (TRANS) {
#pragma unroll
        for (int c = 0; c < NT; ++c)
            out[(size_t)(tn * NT + c) * M + pixm] = acc[c];
    } else {
        float* op = out + (size_t)pixm * C + tn * NT;
#pragma unroll
        for (int c = 0; c < NT; ++c) op[c] = acc[c];
    }
}

extern "C" void kernel_launch(void* const* d_in, const int* in_sizes, int n_in,
                              void* d_out, int out_size, void* d_ws, size_t ws_size,
                              hipStream_t stream) {
    const float* attn    = (const float*)d_in[0];
    const float* w_qkv1  = (const float*)d_in[1];
    const float* b_qkv1  = (const float*)d_in[2];
    const float* w_proj1 = (const float*)d_in[3];
    const float* b_proj1 = (const float*)d_in[4];
    const float* rpb1    = (const float*)d_in[5];
    const float* w_qkv2  = (const float*)d_in[6];
    const float* b_qkv2  = (const float*)d_in[7];
    const float* w_proj2 = (const float*)d_in[8];
    const float* b_proj2 = (const float*)d_in[9];
    const float* rpb2    = (const float*)d_in[10];
    const float* w_qkv3  = (const float*)d_in[11];
    const float* b_qkv3  = (const float*)d_in[12];
    const float* w_proj3 = (const float*)d_in[13];
    const float* b_proj3 = (const float*)d_in[14];
    const float* rpb3    = (const float*)d_in[15];
    const float* w_up1   = (const float*)d_in[16];
    const float* b_up1   = (const float*)d_in[17];
    const float* w_up2   = (const float*)d_in[18];
    const float* b_up2   = (const float*)d_in[19];
    float* out = (float*)d_out;

    float* ws   = (float*)d_ws;
    float* bufB = ws + 2359296;              // qkv   (max 18432*384)
    float* bufD = bufB + 7077888;            // y     (max 4608*64)
    float* wc1  = bufD + 294912;             // 32x192 composed up1->qkv2
    float* bc1  = wc1 + 6144;                // 192
    float* wc2  = bc1 + 192;                 // 64x384 composed up2->qkv3
    float* bc2  = wc2 + 24576;               // 384

    // ---- union: weight composition + stage-1 qkv (independent work) ----
    compose_qkv1<<<72 + 123, 256, 0, stream>>>(
        attn, w_qkv1, b_qkv1, bufB,
        w_up1, b_up1, w_qkv2, b_qkv2, w_up2, b_up2, w_qkv3, b_qkv3,
        wc1, bc1, wc2, bc2);

    // ---- Stage 1 attention+proj: C=32, 24x48, M=1152 ----
    {
        const int H = 24, W = 48, M = H * W;
        na2d_proj<32, 0><<<M / 16, 256, 0, stream>>>(
            bufB, rpb1, w_proj1, b_proj1, bufD, H, W, M);
    }
    // ---- Stage 2: C=64, 48x96, M=4608; qkv2 = up2x(y1) @ wc1 + bc1 ----
    {
        const int H = 48, W = 96, C = 64, M = H * W;
        gemm_rt<64, 64, 4, 0, 1><<<dim3(M / 64, 3), 256, 0, stream>>>(
            bufD, wc1, bc1, bufB, M, 32, 3 * C, C, 1.f / sqrtf((float)C), 24, 48);
        na2d_proj<64, 0><<<M / 16, 256, 0, stream>>>(
            bufB, rpb2, w_proj2, b_proj2, bufD, H, W, M);
    }
    // ---- Stage 3: C=128, 96x192, M=18432; qkv3 = up2x(y2) @ wc2 + bc2 ----
    {
        const int H = 96, W = 192, C = 128, M = H * W;
        gemm_rt<128, 128, 8, 0, 1><<<dim3(M / 128, 3), 256, 0, stream>>>(
            bufD, wc2, bc2, bufB, M, 64, 3 * C, C, 1.f / sqrtf((float)C), 48, 96);
        na2d_proj<128, 1><<<M / 16, 256, 0, stream>>>(
            bufB, rpb3, w_proj3, b_proj3, out, H, W, M);  // -> CHW
    }
}